// Round 1
// baseline (336.852 us; speedup 1.0000x reference)
//
#include <hip/hip_runtime.h>
#include <math.h>

// Problem constants (match reference file).
#define NN 8192        // n_nodes
#define NE 262144      // edges per adjacency list

// Pass 1: row sums straight from the edge lists.
// row_sum[r] = alpha * sum(vals_s where rows_s==r) + (1-alpha) * sum(vals_t where rows_t==r)
// This equals the dense row sum of Af because every col index lands inside the row.
__global__ __launch_bounds__(256) void rowsum_kernel(
        const int* __restrict__ rows_s, const float* __restrict__ vals_s,
        const int* __restrict__ rows_t, const float* __restrict__ vals_t,
        const float* __restrict__ gamma, float* __restrict__ row_sum) {
    int i = blockIdx.x * blockDim.x + threadIdx.x;
    float alpha = 1.0f / (1.0f + expf(-gamma[0]));
    if (i < NE) {
        atomicAdd(&row_sum[rows_s[i]], alpha * vals_s[i]);
    } else {
        int j = i - NE;
        atomicAdd(&row_sum[rows_t[j]], (1.0f - alpha) * vals_t[j]);
    }
}

// Pass 2: scatter normalized values. Zero entries of the dense matrix stay
// zero under row-normalization, so only the ~2E nonzeros are ever written
// (beyond the memset). Division distributes over the scatter-sum.
__global__ __launch_bounds__(256) void scatter_kernel(
        const int* __restrict__ rows_s, const int* __restrict__ cols_s,
        const float* __restrict__ vals_s,
        const int* __restrict__ rows_t, const int* __restrict__ cols_t,
        const float* __restrict__ vals_t,
        const float* __restrict__ gamma, const float* __restrict__ row_sum,
        float* __restrict__ out) {
    int i = blockIdx.x * blockDim.x + threadIdx.x;
    float alpha = 1.0f / (1.0f + expf(-gamma[0]));
    int r, c;
    float v, w;
    if (i < NE) {
        r = rows_s[i]; c = cols_s[i]; v = vals_s[i]; w = alpha;
    } else {
        int j = i - NE;
        r = rows_t[j]; c = cols_t[j]; v = vals_t[j]; w = 1.0f - alpha;
    }
    float s = row_sum[r];
    if (s == 0.0f) s = 1.0f;  // reference: rows with zero sum divide by 1
    atomicAdd(&out[(size_t)r * NN + c], (w * v) / s);
}

extern "C" void kernel_launch(void* const* d_in, const int* in_sizes, int n_in,
                              void* d_out, int out_size, void* d_ws, size_t ws_size,
                              hipStream_t stream) {
    const int*   rows_s = (const int*)  d_in[0];
    const int*   cols_s = (const int*)  d_in[1];
    const float* vals_s = (const float*)d_in[2];
    const int*   rows_t = (const int*)  d_in[3];
    const int*   cols_t = (const int*)  d_in[4];
    const float* vals_t = (const float*)d_in[5];
    const float* gamma  = (const float*)d_in[6];

    float* out     = (float*)d_out;            // [NN*NN] float32
    float* row_sum = (float*)d_ws;             // [NN] float32 scratch

    // d_out / d_ws are poisoned with 0xAA before every call — zero them.
    hipMemsetAsync(d_out, 0, (size_t)NN * NN * sizeof(float), stream);
    hipMemsetAsync(d_ws, 0, (size_t)NN * sizeof(float), stream);

    const int total = 2 * NE;              // 524288 threads
    const int block = 256;
    const int grid  = total / block;       // 2048 blocks

    rowsum_kernel<<<grid, block, 0, stream>>>(rows_s, vals_s, rows_t, vals_t,
                                              gamma, row_sum);
    scatter_kernel<<<grid, block, 0, stream>>>(rows_s, cols_s, vals_s,
                                               rows_t, cols_t, vals_t,
                                               gamma, row_sum, out);
}

// Round 2
// 335.540 us; speedup vs baseline: 1.0039x; 1.0039x over previous
//
#include <hip/hip_runtime.h>
#include <math.h>

#define NN 8192        // n_nodes
#define NE 262144      // edges per adjacency list
#define TOTAL (2*NE)   // 524288

// Workspace layout (ints):
//   cnt    [0      .. 8192)    per-row edge counts
//   off    [8192   .. 16385)   exclusive scan, 8193 entries (off[NN]=TOTAL)
//   cursor [16640  .. 24832)   allocation cursors, initialized = off
//   bcol   [24832  .. 24832+TOTAL)
//   bval   [24832+TOTAL .. 24832+2*TOTAL)   (floats)
#define WS_OFF    8192
#define WS_CUR    16640
#define WS_BCOL   24832
#define WS_BVAL   (24832 + TOTAL)

// Pass 1: per-row edge counts across both lists.
__global__ __launch_bounds__(256) void count_kernel(
        const int* __restrict__ rows_s, const int* __restrict__ rows_t,
        int* __restrict__ cnt) {
    int i = blockIdx.x * blockDim.x + threadIdx.x;
    int r = (i < NE) ? rows_s[i] : rows_t[i - NE];
    atomicAdd(&cnt[r], 1);
}

// Pass 2: single-block exclusive scan of cnt[8192] -> off[8193]; also seeds cursor=off.
__global__ __launch_bounds__(1024) void scan_kernel(
        const int* __restrict__ cnt, int* __restrict__ off, int* __restrict__ cursor) {
    __shared__ int sums[1024];
    int t = threadIdx.x;
    int base = t * 8;
    int local[8];
    int s = 0;
    #pragma unroll
    for (int k = 0; k < 8; k++) { local[k] = s; s += cnt[base + k]; }
    sums[t] = s;
    __syncthreads();
    // Hillis-Steele inclusive scan over the 1024 per-thread totals.
    for (int d = 1; d < 1024; d <<= 1) {
        int v = (t >= d) ? sums[t - d] : 0;
        __syncthreads();
        sums[t] += v;
        __syncthreads();
    }
    int prefix = (t == 0) ? 0 : sums[t - 1];
    #pragma unroll
    for (int k = 0; k < 8; k++) {
        int o = prefix + local[k];
        off[base + k]    = o;
        cursor[base + k] = o;
    }
    if (t == 1023) off[NN] = sums[1023];   // == TOTAL
}

// Pass 3: scatter edges into per-row CSR buckets with pre-blended weights.
__global__ __launch_bounds__(256) void fill_kernel(
        const int* __restrict__ rows_s, const int* __restrict__ cols_s,
        const float* __restrict__ vals_s,
        const int* __restrict__ rows_t, const int* __restrict__ cols_t,
        const float* __restrict__ vals_t,
        const float* __restrict__ gamma,
        int* __restrict__ cursor, int* __restrict__ bcol, float* __restrict__ bval) {
    int i = blockIdx.x * blockDim.x + threadIdx.x;
    float alpha = 1.0f / (1.0f + expf(-gamma[0]));
    int r, c; float v, w;
    if (i < NE) { r = rows_s[i]; c = cols_s[i]; v = vals_s[i]; w = alpha; }
    else { int j = i - NE; r = rows_t[j]; c = cols_t[j]; v = vals_t[j]; w = 1.0f - alpha; }
    int pos = atomicAdd(&cursor[r], 1);
    bcol[pos] = c;
    bval[pos] = w * v;
}

// Pass 4: one block per row. Accumulate in LDS, reduce row sum, normalize,
// stream out coalesced float4. Output is written exactly once (no memset).
__global__ __launch_bounds__(256) void row_kernel(
        const int* __restrict__ off,
        const int* __restrict__ bcol, const float* __restrict__ bval,
        float* __restrict__ out) {
    __shared__ float row[NN];          // 32 KB
    __shared__ float red[4];
    int r = blockIdx.x;
    int t = threadIdx.x;

    #pragma unroll 8
    for (int k = t; k < NN; k += 256) row[k] = 0.0f;
    __syncthreads();

    int start = off[r], end = off[r + 1];
    for (int k = start + t; k < end; k += 256)
        atomicAdd(&row[bcol[k]], bval[k]);
    __syncthreads();

    // Row sum (matches the reference's dense-row reduction up to fp reorder).
    float s = 0.0f;
    #pragma unroll 8
    for (int k = t; k < NN; k += 256) s += row[k];
    #pragma unroll
    for (int o = 32; o > 0; o >>= 1) s += __shfl_down(s, o, 64);
    int wave = t >> 6, lane = t & 63;
    if (lane == 0) red[wave] = s;
    __syncthreads();
    float total = red[0] + red[1] + red[2] + red[3];
    float inv = (total == 0.0f) ? 1.0f : 1.0f / total;

    float4* out4 = (float4*)(out + (size_t)r * NN);
    #pragma unroll 2
    for (int k = t; k < NN / 4; k += 256) {
        float4 x;
        x.x = row[4 * k + 0] * inv;
        x.y = row[4 * k + 1] * inv;
        x.z = row[4 * k + 2] * inv;
        x.w = row[4 * k + 3] * inv;
        out4[k] = x;
    }
}

extern "C" void kernel_launch(void* const* d_in, const int* in_sizes, int n_in,
                              void* d_out, int out_size, void* d_ws, size_t ws_size,
                              hipStream_t stream) {
    const int*   rows_s = (const int*)  d_in[0];
    const int*   cols_s = (const int*)  d_in[1];
    const float* vals_s = (const float*)d_in[2];
    const int*   rows_t = (const int*)  d_in[3];
    const int*   cols_t = (const int*)  d_in[4];
    const float* vals_t = (const float*)d_in[5];
    const float* gamma  = (const float*)d_in[6];

    float* out    = (float*)d_out;
    int*   ws     = (int*)d_ws;
    int*   cnt    = ws;
    int*   off    = ws + WS_OFF;
    int*   cursor = ws + WS_CUR;
    int*   bcol   = ws + WS_BCOL;
    float* bval   = (float*)(ws + WS_BVAL);

    // Zero only the 32 KB counter array (ws is poisoned with 0xAA).
    hipMemsetAsync(cnt, 0, NN * sizeof(int), stream);

    count_kernel<<<TOTAL / 256, 256, 0, stream>>>(rows_s, rows_t, cnt);
    scan_kernel<<<1, 1024, 0, stream>>>(cnt, off, cursor);
    fill_kernel<<<TOTAL / 256, 256, 0, stream>>>(rows_s, cols_s, vals_s,
                                                 rows_t, cols_t, vals_t,
                                                 gamma, cursor, bcol, bval);
    row_kernel<<<NN, 256, 0, stream>>>(off, bcol, bval, out);
}

// Round 4
// 308.861 us; speedup vs baseline: 1.0906x; 1.0864x over previous
//
#include <hip/hip_runtime.h>
#include <math.h>

#define NN 8192        // n_nodes
#define NE 262144      // edges per adjacency list
#define TOTAL (2*NE)   // 524288
#define CAP 128        // bucket capacity per row (mean 64, sd 8; max ~95)

typedef float f4 __attribute__((ext_vector_type(4)));   // native vec: OK for nontemporal builtins

struct Pair { int c; float v; };

// Workspace layout (bytes):
//   [0, 32768)              cnt[8192] row cursors
//   [32768, 32772)          ovf_cnt
//   [65536, 65536+8MB)      bucket Pair[8192][128]
//   [65536+8MB, +128KB)     ovf int4[8192]  (r, c, bits(w*v), 0)
#define BK_OFF (65536)
#define OV_OFF (65536 + (size_t)NN * CAP * 8)

// Single-pass bucket build: blend weight applied at scatter time.
// i<NE handles list s, else list t — branch is block-uniform (256 | NE).
__global__ __launch_bounds__(256) void fill_kernel(
        const int* __restrict__ rows_s, const int* __restrict__ cols_s,
        const float* __restrict__ vals_s,
        const int* __restrict__ rows_t, const int* __restrict__ cols_t,
        const float* __restrict__ vals_t,
        const float* __restrict__ gamma,
        int* __restrict__ cnt, Pair* __restrict__ bucket,
        int* __restrict__ ovf_cnt, int4* __restrict__ ovf) {
    int i = blockIdx.x * blockDim.x + threadIdx.x;
    float alpha = 1.0f / (1.0f + expf(-gamma[0]));
    int r, c; float v, w;
    if (i < NE) { r = rows_s[i]; c = cols_s[i]; v = vals_s[i]; w = alpha; }
    else { int j = i - NE; r = rows_t[j]; c = cols_t[j]; v = vals_t[j]; w = 1.0f - alpha; }
    float wv = w * v;
    int pos = atomicAdd(&cnt[r], 1);
    if (pos < CAP) {
        Pair p; p.c = c; p.v = wv;
        bucket[r * CAP + pos] = p;
    } else {
        // Statistically unreachable at these sizes; kept for correctness.
        int k = atomicAdd(ovf_cnt, 1);
        int4 e; e.x = r; e.y = c; e.z = __float_as_int(wv); e.w = 0;
        ovf[k] = e;
    }
}

// One block per output row. Row sum = sum of the row's bucket values
// (identical addend set as the reference's dense row sum, reordered).
__global__ __launch_bounds__(256) void row_kernel(
        const int* __restrict__ cnt, const Pair* __restrict__ bucket,
        const int* __restrict__ ovf_cnt, const int4* __restrict__ ovf,
        float* __restrict__ out) {
    __shared__ float row[NN];          // 32 KB
    __shared__ float red[4];
    int r = blockIdx.x;
    int t = threadIdx.x;

    f4* row4 = (f4*)row;
    #pragma unroll
    for (int k = t; k < NN / 4; k += 256) {
        f4 z = {0.f, 0.f, 0.f, 0.f};
        row4[k] = z;
    }
    int n = cnt[r];
    int nb = n < CAP ? n : CAP;
    __syncthreads();

    float part = 0.0f;
    for (int k = t; k < nb; k += 256) {
        Pair p = bucket[r * CAP + k];
        part += p.v;
        atomicAdd(&row[p.c], p.v);
    }
    int no = *ovf_cnt;
    if (no > 0) {                       // cold path, normally 0 entries
        for (int k = t; k < no; k += 256) {
            int4 e = ovf[k];
            if (e.x == r) {
                float v = __int_as_float(e.z);
                part += v;
                atomicAdd(&row[e.y], v);
            }
        }
    }

    #pragma unroll
    for (int o = 32; o > 0; o >>= 1) part += __shfl_down(part, o, 64);
    if ((t & 63) == 0) red[t >> 6] = part;
    __syncthreads();                    // also fences the LDS scatter atomics
    float total = red[0] + red[1] + red[2] + red[3];
    float inv = (total == 0.0f) ? 1.0f : 1.0f / total;

    f4* out4 = (f4*)(out + (size_t)r * NN);
    #pragma unroll
    for (int k = t; k < NN / 4; k += 256) {
        f4 x = row4[k];
        x *= inv;
        __builtin_nontemporal_store(x, &out4[k]);
    }
}

extern "C" void kernel_launch(void* const* d_in, const int* in_sizes, int n_in,
                              void* d_out, int out_size, void* d_ws, size_t ws_size,
                              hipStream_t stream) {
    const int*   rows_s = (const int*)  d_in[0];
    const int*   cols_s = (const int*)  d_in[1];
    const float* vals_s = (const float*)d_in[2];
    const int*   rows_t = (const int*)  d_in[3];
    const int*   cols_t = (const int*)  d_in[4];
    const float* vals_t = (const float*)d_in[5];
    const float* gamma  = (const float*)d_in[6];

    float* out     = (float*)d_out;
    char*  ws      = (char*)d_ws;
    int*   cnt     = (int*)ws;                    // [NN]
    int*   ovf_cnt = (int*)(ws + 32768);          // [1]
    Pair*  bucket  = (Pair*)(ws + BK_OFF);        // [NN*CAP]
    int4*  ovf     = (int4*)(ws + OV_OFF);        // [8192]

    // Zero cursors + overflow counter (ws is poisoned with 0xAA).
    (void)hipMemsetAsync(ws, 0, 32772, stream);

    fill_kernel<<<TOTAL / 256, 256, 0, stream>>>(rows_s, cols_s, vals_s,
                                                 rows_t, cols_t, vals_t,
                                                 gamma, cnt, bucket, ovf_cnt, ovf);
    row_kernel<<<NN, 256, 0, stream>>>(cnt, bucket, ovf_cnt, ovf, out);
}